// Round 2
// baseline (88.176 us; speedup 1.0000x reference)
//
#include <hip/hip_runtime.h>
#include <cmath>

#define NPTS 12288
#define NB   64
#define NCH  9
#define NKC  10
#define TILE 384
#define BIGF 1000000.0f
#define SENT 1e30f

// ---------------------------------------------------------------------------
// K1: block = (chunk s, batch b), 576 threads = 9 waves (wave w = channel w).
// Stage a 384-point tile into LDS with fully-coalesced float4 loads
// (kpts records padded 24->25 floats => conflict-free strided reads), then
// each wave computes its channel's keys from LDS, keeps a per-lane sorted
// top-10, and a 10-round shuffle pop-min merge emits the wave top-10.
// ---------------------------------------------------------------------------
__global__ __launch_bounds__(576)
void k1_partial_topk(const float* __restrict__ kpts,  // (64,12288,8,3)
                     const float* __restrict__ cpt,   // (64,12288,1,3)
                     const float* __restrict__ seg,   // (64,12288,2)
                     float* __restrict__ wval,
                     int*   __restrict__ widx,
                     int S)
{
    const int s    = blockIdx.x;
    const int b    = blockIdx.y;
    const int tid  = threadIdx.x;
    const int w    = tid >> 6;     // wave id == channel
    const int lane = tid & 63;
    const int P    = NPTS / S;     // points in this chunk (multiple of 384)
    const int i0   = s * P;

    __shared__ float sk[TILE * 25];   // kpts tile, padded stride 25 floats
    __shared__ float sc[TILE * 3];    // cpt tile
    __shared__ float sm[TILE];        // mask tile

    float v[NKC]; int id[NKC];
#pragma unroll
    for (int j = 0; j < NKC; ++j) { v[j] = SENT; id[j] = 0; }

    for (int t0 = 0; t0 < P; t0 += TILE) {
        const int ibase = i0 + t0;

        // ---- stage kpts: 384*24 floats = 2304 float4, 4 per thread ----
        const float4* gk = (const float4*)(kpts + ((size_t)b * NPTS + ibase) * 24);
#pragma unroll
        for (int k = 0; k < 4; ++k) {
            int q = tid + k * 576;             // q < 2304; 24%4==0 -> no record straddle
            float4 val = gk[q];
            int p = q / 6;                     // record (point)
            int r = (q % 6) * 4;               // float offset within record
            float* dst = &sk[p * 25 + r];
            dst[0] = val.x; dst[1] = val.y; dst[2] = val.z; dst[3] = val.w;
        }
        // ---- stage cpt: 1152 floats = 288 float4 ----
        if (tid < 288) {
            const float4* gc = (const float4*)(cpt + ((size_t)b * NPTS + ibase) * 3);
            ((float4*)sc)[tid] = gc[tid];
        }
        // ---- stage seg -> mask: 768 floats = 192 float4 (2 points each) ----
        if (tid < 192) {
            const float4* gs = (const float4*)(seg + ((size_t)b * NPTS + ibase) * 2);
            float4 sv = gs[tid];
            sm[2 * tid]     = (sv.y > sv.x) ? 1.0f : BIGF;  // argmax==1 <=> seg1>seg0
            sm[2 * tid + 1] = (sv.w > sv.z) ? 1.0f : BIGF;
        }
        __syncthreads();

        // ---- compute keys for this wave's channel ----
#pragma unroll
        for (int m = 0; m < 6; ++m) {
            const int p = m * 64 + lane;
            float x, y, z;
            if (w < 8) {                        // wave-uniform branch
                const int base = p * 25 + w * 3;
                x = sk[base]; y = sk[base + 1]; z = sk[base + 2];
            } else {
                const int base = p * 3;
                x = sc[base]; y = sc[base + 1]; z = sc[base + 2];
            }
            float n2  = __fadd_rn(__fadd_rn(__fmul_rn(x, x), __fmul_rn(y, y)),
                                  __fmul_rn(z, z));
            float key = __fmul_rn(sqrtf(n2), sm[p]);
            if (key < v[NKC - 1]) {
                v[NKC - 1] = key; id[NKC - 1] = ibase + p;
#pragma unroll
                for (int q = NKC - 1; q > 0; --q) {
                    if (v[q] < v[q - 1]) {
                        float tv = v[q]; v[q] = v[q - 1]; v[q - 1] = tv;
                        int   ti = id[q]; id[q] = id[q - 1]; id[q - 1] = ti;
                    }
                }
            }
        }
        __syncthreads();
    }

    // ---- 10-round pop-min merge across the wave (tie-break: lower index) ----
    float outv = 0.0f; int outi = 0;
#pragma unroll
    for (int r = 0; r < NKC; ++r) {
        float cv = v[0]; int ci = id[0]; int cl = lane;
#pragma unroll
        for (int m = 32; m; m >>= 1) {
            float ov = __shfl_xor(cv, m);
            int   oi = __shfl_xor(ci, m);
            int   ol = __shfl_xor(cl, m);
            if (ov < cv || (ov == cv && oi < ci)) { cv = ov; ci = oi; cl = ol; }
        }
        if (lane == cl) {
#pragma unroll
            for (int q = 0; q < NKC - 1; ++q) { v[q] = v[q + 1]; id[q] = id[q + 1]; }
            v[NKC - 1] = SENT;
        }
        if (lane == r) { outv = cv; outi = ci; }
    }
    if (lane < NKC) {
        size_t o = ((((size_t)b * S + s) * NCH) + w) * NKC + lane;
        wval[o] = outv; widx[o] = outi;
    }
}

// ---------------------------------------------------------------------------
// K2: one block per batch, 576 threads = 9 waves (wave = channel).
// Wave-parallel pop-min merge of the S*10 partials, lanes 0..9 gather the
// candidates into LDS, 27 threads do the exact sequential clustering,
// thread 0 does the 3x3 Jacobi SVD -> Kabsch R, t.
// ---------------------------------------------------------------------------

#define JROT(P, Q) do {                                                        \
    float aa = G[0][P]*G[0][P] + G[1][P]*G[1][P] + G[2][P]*G[2][P];            \
    float bb = G[0][Q]*G[0][Q] + G[1][Q]*G[1][Q] + G[2][Q]*G[2][Q];            \
    float gg = G[0][P]*G[0][Q] + G[1][P]*G[1][Q] + G[2][P]*G[2][Q];            \
    if (fabsf(gg) > 1e-30f) {                                                  \
        float zeta = (bb - aa) / (2.0f * gg);                                  \
        float tt = copysignf(1.0f, zeta) / (fabsf(zeta) + sqrtf(1.0f + zeta*zeta)); \
        float cc = 1.0f / sqrtf(1.0f + tt * tt);                               \
        float ss = cc * tt;                                                    \
        _Pragma("unroll")                                                      \
        for (int ii = 0; ii < 3; ++ii) {                                       \
            float gp = G[ii][P], gq = G[ii][Q];                                \
            G[ii][P] = cc*gp - ss*gq; G[ii][Q] = ss*gp + cc*gq;                \
            float vp = Vv[ii][P], vq = Vv[ii][Q];                              \
            Vv[ii][P] = cc*vp - ss*vq; Vv[ii][Q] = ss*vp + cc*vq;              \
        }                                                                      \
    }                                                                          \
} while (0)

#define CSWAP(P, Q) do { if (s##P < s##Q) {                                    \
    float t_ = s##P; s##P = s##Q; s##Q = t_;                                   \
    _Pragma("unroll")                                                          \
    for (int ii = 0; ii < 3; ++ii) {                                           \
        t_ = U[ii][P];  U[ii][P]  = U[ii][Q];  U[ii][Q]  = t_;                 \
        t_ = Vv[ii][P]; Vv[ii][P] = Vv[ii][Q]; Vv[ii][Q] = t_;                 \
    }                                                                          \
} } while (0)

__global__ __launch_bounds__(576)
void k2_cluster_svd(const float* __restrict__ pcld,  // (64,12288,3)
                    const float* __restrict__ kpts,
                    const float* __restrict__ cpt,
                    const float* __restrict__ mesh,  // (64,9,3)
                    const float* __restrict__ wval,
                    const int*   __restrict__ widx,
                    float* __restrict__ out,
                    int S)
{
    const int b    = blockIdx.x;
    const int tid  = threadIdx.x;
    const int c    = tid >> 6;     // wave id == channel
    const int lane = tid & 63;

    __shared__ float scand[NCH][NKC][3];
    __shared__ float voted[NCH][3];

    // ---- per-lane sorted sublist of the S*10 partials (<=5 each) ----
    const int E = S * NKC;
    float v[5]; int id[5];
#pragma unroll
    for (int j = 0; j < 5; ++j) { v[j] = SENT; id[j] = 0; }
#pragma unroll
    for (int j = 0; j < 5; ++j) {
        int e = lane + j * 64;
        if (e < E) {
            int ss = e / NKC, rr = e % NKC;
            size_t o = ((((size_t)b * S + ss) * NCH) + c) * NKC + rr;
            float key = wval[o]; int ki = widx[o];
            if (key < v[4]) {
                v[4] = key; id[4] = ki;
#pragma unroll
                for (int q = 4; q > 0; --q) {
                    if (v[q] < v[q - 1]) {
                        float tv = v[q]; v[q] = v[q - 1]; v[q - 1] = tv;
                        int   ti = id[q]; id[q] = id[q - 1]; id[q - 1] = ti;
                    }
                }
            }
        }
    }
    // ---- 10-round pop-min merge; lane q keeps q-th smallest ----
    float mv = 0.0f; int mi = 0;
#pragma unroll
    for (int r = 0; r < NKC; ++r) {
        float cv = v[0]; int ci = id[0]; int cl = lane;
#pragma unroll
        for (int m = 32; m; m >>= 1) {
            float ov = __shfl_xor(cv, m);
            int   oi = __shfl_xor(ci, m);
            int   ol = __shfl_xor(cl, m);
            if (ov < cv || (ov == cv && oi < ci)) { cv = ov; ci = oi; cl = ol; }
        }
        if (lane == cl) {
#pragma unroll
            for (int q = 0; q < 4; ++q) { v[q] = v[q + 1]; id[q] = id[q + 1]; }
            v[4] = SENT;
        }
        if (lane == r) { mv = cv; mi = ci; }
    }
    // ---- lanes 0..9 gather candidates ----
    if (lane < NKC) {
        const int i = mi;
        const float* pp = pcld + ((size_t)b * NPTS + i) * 3;
        const float* op = (c < 8) ? (kpts + (((size_t)b * NPTS + i) * 8 + c) * 3)
                                  : (cpt  + ((size_t)b * NPTS + i) * 3);
        scand[c][lane][0] = __fadd_rn(pp[0], op[0]);
        scand[c][lane][1] = __fadd_rn(pp[1], op[1]);
        scand[c][lane][2] = __fadd_rn(pp[2], op[2]);
    }
    __syncthreads();

    // ---- 27 threads: exact sequential clustering per (channel, coord) ----
    if (tid < NCH * 3) {
        const int cc = tid / 3, d = tid % 3;
        float sum = 0.0f;
#pragma unroll
        for (int q = 0; q < NKC; ++q) sum = __fadd_rn(sum, scand[cc][q][d]);
        float mu = sum / 10.0f;
        float var = 0.0f;
#pragma unroll
        for (int q = 0; q < NKC; ++q) {
            float dq = __fsub_rn(scand[cc][q][d], mu);
            var = __fadd_rn(var, __fmul_rn(dq, dq));
        }
        float sd = sqrtf(var / 10.0f);
        float fs = 0.0f; int cnt = 0;
#pragma unroll
        for (int q = 0; q < NKC; ++q) {
            float x = scand[cc][q][d];
            if (fabsf(__fsub_rn(x, mu)) < sd) {
                fs = __fadd_rn(fs, x);
                if (x != 0.0f) cnt++;
            }
        }
        float res = fs / (float)(cnt > 0 ? cnt : 1);
        voted[cc][d] = res;
        out[768 + ((size_t)b * NCH + cc) * 3 + d] = res;  // kpts_voted
    }
    __syncthreads();

    // ---- thread 0: Kabsch via 3x3 one-sided Jacobi SVD ----
    if (tid == 0) {
        float Ax[9], Ay[9], Az[9], Bx[9], By[9], Bz[9];
#pragma unroll
        for (int n = 0; n < 9; ++n) {
            const float* mp = mesh + ((size_t)b * 9 + n) * 3;
            Ax[n] = mp[0]; Ay[n] = mp[1]; Az[n] = mp[2];
            Bx[n] = voted[n][0]; By[n] = voted[n][1]; Bz[n] = voted[n][2];
        }
        float cax = 0, cay = 0, caz = 0, cbx = 0, cby = 0, cbz = 0;
#pragma unroll
        for (int n = 0; n < 9; ++n) {
            cax += Ax[n]; cay += Ay[n]; caz += Az[n];
            cbx += Bx[n]; cby += By[n]; cbz += Bz[n];
        }
        cax /= 9.0f; cay /= 9.0f; caz /= 9.0f;
        cbx /= 9.0f; cby /= 9.0f; cbz /= 9.0f;

        float H[3][3] = {{0,0,0},{0,0,0},{0,0,0}};
#pragma unroll
        for (int n = 0; n < 9; ++n) {
            float a0 = Ax[n]-cax, a1 = Ay[n]-cay, a2 = Az[n]-caz;
            float b0 = Bx[n]-cbx, b1 = By[n]-cby, b2 = Bz[n]-cbz;
            H[0][0]+=a0*b0; H[0][1]+=a0*b1; H[0][2]+=a0*b2;
            H[1][0]+=a1*b0; H[1][1]+=a1*b1; H[1][2]+=a1*b2;
            H[2][0]+=a2*b0; H[2][1]+=a2*b1; H[2][2]+=a2*b2;
        }

        float G[3][3], Vv[3][3];
#pragma unroll
        for (int i = 0; i < 3; ++i)
#pragma unroll
            for (int j = 0; j < 3; ++j) {
                G[i][j]  = H[i][j];
                Vv[i][j] = (i == j) ? 1.0f : 0.0f;
            }
        for (int sw = 0; sw < 12; ++sw) { JROT(0,1); JROT(0,2); JROT(1,2); }

        float s0 = sqrtf(G[0][0]*G[0][0] + G[1][0]*G[1][0] + G[2][0]*G[2][0]);
        float s1 = sqrtf(G[0][1]*G[0][1] + G[1][1]*G[1][1] + G[2][1]*G[2][1]);
        float s2 = sqrtf(G[0][2]*G[0][2] + G[1][2]*G[1][2] + G[2][2]*G[2][2]);
        float r0 = 1.0f / fmaxf(s0, 1e-30f);
        float r1 = 1.0f / fmaxf(s1, 1e-30f);
        float r2 = 1.0f / fmaxf(s2, 1e-30f);
        float U[3][3];
#pragma unroll
        for (int i = 0; i < 3; ++i) {
            U[i][0] = G[i][0] * r0; U[i][1] = G[i][1] * r1; U[i][2] = G[i][2] * r2;
        }
        CSWAP(0, 1); CSWAP(1, 2); CSWAP(0, 1);   // descending singular values

        float R0[3][3];
#pragma unroll
        for (int i = 0; i < 3; ++i)
#pragma unroll
            for (int j = 0; j < 3; ++j)
                R0[i][j] = Vv[i][0]*U[j][0] + Vv[i][1]*U[j][1] + Vv[i][2]*U[j][2];
        float det = R0[0][0]*(R0[1][1]*R0[2][2] - R0[1][2]*R0[2][1])
                  - R0[0][1]*(R0[1][0]*R0[2][2] - R0[1][2]*R0[2][0])
                  + R0[0][2]*(R0[1][0]*R0[2][1] - R0[1][1]*R0[2][0]);
        float dsgn = (det >= 0.0f) ? 1.0f : -1.0f;

        float R[3][3];
#pragma unroll
        for (int i = 0; i < 3; ++i)
#pragma unroll
            for (int j = 0; j < 3; ++j) {
                R[i][j] = Vv[i][0]*U[j][0] + Vv[i][1]*U[j][1] + dsgn*Vv[i][2]*U[j][2];
                out[(size_t)b * 9 + i * 3 + j] = R[i][j];
            }
#pragma unroll
        for (int i = 0; i < 3; ++i) {
            float ti = ((i==0)?cbx:(i==1)?cby:cbz)
                     - (R[i][0]*cax + R[i][1]*cay + R[i][2]*caz);
            out[576 + (size_t)b * 3 + i] = ti;
        }
    }
}

extern "C" void kernel_launch(void* const* d_in, const int* in_sizes, int n_in,
                              void* d_out, int out_size, void* d_ws, size_t ws_size,
                              hipStream_t stream)
{
    const float* pcld = (const float*)d_in[0];
    const float* kpts = (const float*)d_in[1];
    const float* cpt  = (const float*)d_in[2];
    const float* seg  = (const float*)d_in[3];
    const float* mesh = (const float*)d_in[4];
    float* out = (float*)d_out;

    // chunk count S: NPTS/S must be a multiple of TILE=384 -> S in {32,16,8,...}
    int S = 32;
    while (S > 1 && (size_t)NB * S * NCH * NKC * 8ull > ws_size) S >>= 1;

    float* wval = (float*)d_ws;
    int*   widx = (int*)((char*)d_ws + (size_t)NB * S * NCH * NKC * sizeof(float));

    dim3 g1(S, NB), b1(576);
    k1_partial_topk<<<g1, b1, 0, stream>>>(kpts, cpt, seg, wval, widx, S);
    k2_cluster_svd<<<NB, 576, 0, stream>>>(pcld, kpts, cpt, mesh, wval, widx, out, S);
}